// Round 7
// baseline (431.467 us; speedup 1.0000x reference)
//
#include <hip/hip_runtime.h>
#include <math.h>

#define B_   128
#define N_   1024
#define D_   256
#define G_   64
#define GSZ_ 3
#define RD_  16
#define KD_  64
#define PD_  64
#define NF_  64
#define Q_   (G_*GSZ_)   // 192

typedef __attribute__((ext_vector_type(8))) short bf16x8;   // 8 bf16 = 4 VGPRs
typedef __attribute__((ext_vector_type(4))) float f32x4;

__device__ __forceinline__ unsigned short f2bf(float f) {
    unsigned int u = __float_as_uint(f);
    u += 0x7fffu + ((u >> 16) & 1u);       // RNE
    return (unsigned short)(u >> 16);
}

// ---------------------------------------------------------------------------
// prep_kernel: fused one-time prep (saves 3 launch overheads).
//   blocks   0..31 : wb2  — Wb[col][d] bf16 (col = qk*1024 + r*64 + p)
//   blocks  32..95 : wkt  — WkTb[kd][d] = bf16(Wk_map[d][kd])
//   blocks  96..143: qeb  — bf16(query_emb * 0.125)
//   blocks 144..147: coef — S3 orbit-collapsed filter coefs (c1, c2)
// ---------------------------------------------------------------------------
__global__ __launch_bounds__(256)
void prep_kernel(const float* __restrict__ filters,
                 const float* __restrict__ qe,
                 const float* __restrict__ Wk_map,
                 const float* __restrict__ Wq,
                 const float* __restrict__ Wk,
                 float* __restrict__ coef,
                 unsigned short* __restrict__ qeb,
                 unsigned short* __restrict__ WkTb,
                 unsigned short* __restrict__ Wb) {
    __shared__ unsigned short wt[64 * 264];
    int bb = blockIdx.x, t = threadIdx.x;
    if (bb < 32) {
        int qk = bb >> 4, r = bb & 15;
        const float* W = qk ? Wk : Wq;
#pragma unroll
        for (int i = 0; i < 16; ++i) {
            int flat = i * 256 + t;            // 4096: 256 d x 16 p4
            int d = flat >> 4, p4 = flat & 15;
            float4 v = *(const float4*)(W + ((size_t)r * 256 + d) * 64 + p4 * 4);
            wt[(p4 * 4 + 0) * 264 + d] = f2bf(v.x);
            wt[(p4 * 4 + 1) * 264 + d] = f2bf(v.y);
            wt[(p4 * 4 + 2) * 264 + d] = f2bf(v.z);
            wt[(p4 * 4 + 3) * 264 + d] = f2bf(v.w);
        }
        __syncthreads();
#pragma unroll
        for (int i = 0; i < 8; ++i) {
            int flat = i * 256 + t;            // 2048: 64 p x 32 segs
            int p = flat >> 5, seg = flat & 31;
            *(uint4*)(Wb + ((size_t)(qk * 1024 + r * 64 + p)) * 256 + seg * 8) =
                *(const uint4*)(&wt[p * 264 + seg * 8]);
        }
    } else if (bb < 96) {
        int i = (bb - 32) * 256 + t;           // [0, 16384)
        int kd = i >> 8, d = i & 255;
        WkTb[kd * 256 + d] = f2bf(Wk_map[d * 64 + kd]);
    } else if (bb < 144) {
        int i = (bb - 96) * 256 + t;
        if (i < Q_ * KD_) qeb[i] = f2bf(qe[i] * 0.125f);
    } else {
        int flat = (bb - 144) * 256 + t;
        if (flat < NF_ * RD_) {
            int f = flat >> 4, r = flat & 15;
            const float* F = filters + f * 144 + r;
            float diag = F[0] + F[48 + 16] + F[96 + 32];
            float all = 0.f;
#pragma unroll
            for (int u = 0; u < 3; ++u)
#pragma unroll
                for (int v = 0; v < 3; ++v) all += F[u * 48 + v * 16];
            float a = diag * (1.f / 3.f);
            float b = (all - diag) * (1.f / 6.f);
            coef[f * 16 + r] = a - b;
            coef[1024 + f * 16 + r] = b;
        }
    }
}

// ---------------------------------------------------------------------------
// xt_kernel: xTb[b][d][n] = bf16(x[b][n][d]). Tile 128n x 64d through LDS.
// ---------------------------------------------------------------------------
__global__ __launch_bounds__(256)
void xt_kernel(const float* __restrict__ x,
               unsigned short* __restrict__ xTb) {
    __shared__ float xs[128][65];
    int b = blockIdx.z, d0 = blockIdx.y * 64, n0 = blockIdx.x * 128;
    int t = threadIdx.x;
#pragma unroll
    for (int i = 0; i < 8; ++i) {
        int f = i * 256 + t;
        int row = f >> 4, c4 = f & 15;       // 128 n-rows x 16 float4
        float4 v = *(const float4*)(x + ((size_t)b * N_ + n0 + row) * D_ + d0 + c4 * 4);
        xs[row][c4 * 4 + 0] = v.x; xs[row][c4 * 4 + 1] = v.y;
        xs[row][c4 * 4 + 2] = v.z; xs[row][c4 * 4 + 3] = v.w;
    }
    __syncthreads();
#pragma unroll
    for (int i = 0; i < 4; ++i) {
        int f = i * 256 + t;
        int dr = f >> 4, seg = f & 15;       // 64 d-rows x 16 n-chunks of 8
        uint4 uv;
        unsigned int* up = (unsigned int*)&uv;
#pragma unroll
        for (int j = 0; j < 4; ++j) {
            unsigned int lo = f2bf(xs[seg * 8 + 2 * j][dr]);
            unsigned int hi = f2bf(xs[seg * 8 + 2 * j + 1][dr]);
            up[j] = lo | (hi << 16);
        }
        *(uint4*)(xTb + ((size_t)b * D_ + d0 + dr) * N_ + n0 + seg * 8) = uv;
    }
}

// ---------------------------------------------------------------------------
// kproj2: k = x@Wk_map + PE -> kb bf16 [b][n][kd] via MFMA on C[kd][n].
// ---------------------------------------------------------------------------
#define WKP 264   // 256+8 bf16 pad, 16B-aligned rows

__global__ __launch_bounds__(256, 2)
void kproj2_kernel(const float* __restrict__ x,
                   const unsigned short* __restrict__ WkTb,
                   unsigned short* __restrict__ kb) {
    __shared__ unsigned short wkts[64 * WKP];
    __shared__ unsigned short xs[64 * WKP];
    __shared__ unsigned short Ks[64 * 72];
    int b = blockIdx.y, n0 = blockIdx.x * 64;
    int t = threadIdx.x, w = t >> 6, lane = t & 63;
    int quad = lane >> 4, lcol = lane & 15;

#pragma unroll
    for (int i = 0; i < 8; ++i) {
        int f = i * 256 + t;
        int row = f >> 5, seg = f & 31;
        *(uint4*)(&wkts[row * WKP + seg * 8]) = *(const uint4*)(WkTb + row * 256 + seg * 8);
    }
#pragma unroll
    for (int i = 0; i < 16; ++i) {
        int f = i * 256 + t;
        int row = f >> 6, c4 = f & 63;
        float4 v = *(const float4*)(x + ((size_t)b * N_ + n0 + row) * D_ + c4 * 4);
        uint2 uv;
        uv.x = (unsigned int)f2bf(v.x) | ((unsigned int)f2bf(v.y) << 16);
        uv.y = (unsigned int)f2bf(v.z) | ((unsigned int)f2bf(v.w) << 16);
        *(uint2*)(&xs[row * WKP + c4 * 4]) = uv;
    }
    __syncthreads();

    f32x4 z[4];
#pragma unroll
    for (int mt = 0; mt < 4; ++mt) z[mt] = (f32x4)(0.f);
#pragma unroll
    for (int kk = 0; kk < 8; ++kk) {
        bf16x8 bf = *(const bf16x8*)(&xs[(w * 16 + lcol) * WKP + kk * 32 + quad * 8]);
#pragma unroll
        for (int mt = 0; mt < 4; ++mt) {
            bf16x8 af = *(const bf16x8*)(&wkts[(mt * 16 + lcol) * WKP + kk * 32 + quad * 8]);
            z[mt] = __builtin_amdgcn_mfma_f32_16x16x32_bf16(af, bf, z[mt], 0, 0, 0);
        }
    }

    int nl = w * 16 + lcol;
    int n = n0 + nl;
#pragma unroll
    for (int mt = 0; mt < 4; ++mt)
#pragma unroll
        for (int r = 0; r < 4; ++r) {
            int kd = mt * 16 + quad * 4 + r;
            float freq  = expf(-(float)(kd >> 1) * (logf(10000.0f) / 32.0f));
            float angle = (float)n * freq;
            float pe    = (kd & 1) ? cosf(angle) : sinf(angle);
            Ks[nl * 72 + kd] = f2bf(z[mt][r] + pe);
        }
    __syncthreads();

#pragma unroll
    for (int i = 0; i < 2; ++i) {
        int f = i * 256 + t;
        int row = f >> 3, seg = f & 7;
        *(uint4*)(kb + ((size_t)b * N_ + n0 + row) * KD_ + seg * 8) =
            *(const uint4*)(&Ks[row * 72 + seg * 8]);
    }
}

// ---------------------------------------------------------------------------
// attn4: per block = (b, q-half of 96), 512 threads. Chunks of 128 n.
// S: wave w owns n-cols w*16+lcol. PV: wave w owns d-tiles {w, 8+w}.
// B-frags straight from global; only the P C->A LDS round trip syncs.
// ---------------------------------------------------------------------------
#define PSP2 136   // 128+8

__global__ __launch_bounds__(512, 2)
void attn4_kernel(const unsigned short* __restrict__ qeb,
                  const unsigned short* __restrict__ kb,
                  const unsigned short* __restrict__ xTb,
                  unsigned short* __restrict__ gobj) {
    __shared__ unsigned short ps[96 * PSP2];
    __shared__ float Rs[96][8];
    __shared__ float invs[96];

    int b = blockIdx.x >> 1, qh = blockIdx.x & 1;
    int t = threadIdx.x, w = t >> 6, lane = t & 63;
    int quad = lane >> 4, lcol = lane & 15;
    int q0 = qh * 96;

    bf16x8 qef[6][2];
#pragma unroll
    for (int mt = 0; mt < 6; ++mt)
#pragma unroll
        for (int ks = 0; ks < 2; ++ks)
            qef[mt][ks] = *(const bf16x8*)(qeb + (q0 + mt * 16 + lcol) * KD_ + ks * 32 + quad * 8);

    f32x4 acc[2][6];
#pragma unroll
    for (int i = 0; i < 2; ++i)
#pragma unroll
        for (int mt = 0; mt < 6; ++mt) acc[i][mt] = (f32x4)(0.f);
    float rsum[6][4];
#pragma unroll
    for (int mt = 0; mt < 6; ++mt)
#pragma unroll
        for (int r = 0; r < 4; ++r) rsum[mt][r] = 0.f;

    const unsigned short* kbB = kb + (size_t)b * N_ * KD_;
    const unsigned short* xtB = xTb + (size_t)b * D_ * N_;

    for (int c = 0; c < 8; ++c) {
        f32x4 s[6];
#pragma unroll
        for (int mt = 0; mt < 6; ++mt) s[mt] = (f32x4)(0.f);
#pragma unroll
        for (int ks = 0; ks < 2; ++ks) {
            bf16x8 bf = *(const bf16x8*)(kbB + (size_t)(c * 128 + w * 16 + lcol) * KD_ + ks * 32 + quad * 8);
#pragma unroll
            for (int mt = 0; mt < 6; ++mt)
                s[mt] = __builtin_amdgcn_mfma_f32_16x16x32_bf16(qef[mt][ks], bf, s[mt], 0, 0, 0);
        }
#pragma unroll
        for (int mt = 0; mt < 6; ++mt)
#pragma unroll
            for (int r = 0; r < 4; ++r) {
                float e = __expf(s[mt][r]);
                s[mt][r] = e;
                rsum[mt][r] += e;
            }
        __syncthreads();   // prior chunk's PV done reading ps
#pragma unroll
        for (int mt = 0; mt < 6; ++mt)
#pragma unroll
            for (int r = 0; r < 4; ++r)
                ps[(mt * 16 + quad * 4 + r) * PSP2 + w * 16 + lcol] = f2bf(s[mt][r]);
        __syncthreads();

#pragma unroll
        for (int ks = 0; ks < 4; ++ks) {
            bf16x8 af[6];
#pragma unroll
            for (int mt = 0; mt < 6; ++mt)
                af[mt] = *(const bf16x8*)(ps + (mt * 16 + lcol) * PSP2 + ks * 32 + quad * 8);
#pragma unroll
            for (int i = 0; i < 2; ++i) {
                int dt = i * 8 + w;
                bf16x8 bf = *(const bf16x8*)(xtB + (size_t)(dt * 16 + lcol) * N_ + c * 128 + ks * 32 + quad * 8);
#pragma unroll
                for (int mt = 0; mt < 6; ++mt)
                    acc[i][mt] = __builtin_amdgcn_mfma_f32_16x16x32_bf16(af[mt], bf, acc[i][mt], 0, 0, 0);
            }
        }
    }

#pragma unroll
    for (int mt = 0; mt < 6; ++mt)
#pragma unroll
        for (int r = 0; r < 4; ++r) {
            float v = rsum[mt][r];
            v += __shfl_xor(v, 1, 64);
            v += __shfl_xor(v, 2, 64);
            v += __shfl_xor(v, 4, 64);
            v += __shfl_xor(v, 8, 64);
            rsum[mt][r] = v;
        }
    if (lcol == 0) {
#pragma unroll
        for (int mt = 0; mt < 6; ++mt)
#pragma unroll
            for (int r = 0; r < 4; ++r)
                Rs[mt * 16 + quad * 4 + r][w] = rsum[mt][r];
    }
    __syncthreads();
    if (t < 96) {
        float s8 = 0.f;
#pragma unroll
        for (int ww = 0; ww < 8; ++ww) s8 += Rs[t][ww];
        invs[t] = 1.0f / s8;
    }
    __syncthreads();

    unsigned short* gB = gobj + ((size_t)b * Q_ + q0) * D_;
#pragma unroll
    for (int i = 0; i < 2; ++i) {
        int dt = i * 8 + w;
#pragma unroll
        for (int mt = 0; mt < 6; ++mt)
#pragma unroll
            for (int r = 0; r < 4; ++r) {
                int q = mt * 16 + quad * 4 + r;
                gB[q * D_ + dt * 16 + lcol] = f2bf(acc[i][mt][r] * invs[q]);
            }
    }
}

// ---------------------------------------------------------------------------
// rel5: rel4 with the r-loop split across 2 blocks (grid 1024 -> 4 blocks/CU,
// 16 waves/CU). Per block: 16 bg, 8 r. A staged once in LDS; main loop:
// 2 global L2-resident Wb frags + 4 LDS A-frags + 8 MFMA per kk, no barriers.
// Partial coef-dot combined via fp32 atomicAdd (out zeroed by memset).
// ---------------------------------------------------------------------------
#define AP4 264

__global__ __launch_bounds__(256, 4)
void rel5_kernel(const unsigned short* __restrict__ gobj,
                 const unsigned short* __restrict__ Wb,
                 const float* __restrict__ coef,
                 float* __restrict__ out) {
    __shared__ unsigned short As[64 * AP4];
    __shared__ float Tp[4 * 16 * 2 * 8];   // [w][bgl(16)][T1|T2][rr(8)] = 4KB

    int t = threadIdx.x, w = t >> 6, lane = t & 63;
    int quad = lane >> 4, lcol = lane & 15;
    int bg0 = (blockIdx.x >> 1) * 16;
    int rh  = blockIdx.x & 1;
    int pcol = w * 16 + lcol;

    // zero pad rows (row%4==3): 16 rows x 32 uint4
#pragma unroll
    for (int i = 0; i < 2; ++i) {
        int idx = i * 256 + t;
        int r3 = idx >> 5, c4 = idx & 31;
        uint4 zz; zz.x = zz.y = zz.z = zz.w = 0u;
        *(uint4*)(&As[(r3 * 4 + 3) * AP4 + c4 * 8]) = zz;
    }
    // stage 48 gobj rows, row = (j/3)*4 + j%3
#pragma unroll
    for (int i = 0; i < 6; ++i) {
        int idx = i * 256 + t;
        int j = idx >> 5, c4 = idx & 31;
        *(uint4*)(&As[((j / 3) * 4 + (j % 3)) * AP4 + c4 * 8]) =
            *(const uint4*)(gobj + ((size_t)(bg0 * 3 + j)) * 256 + c4 * 8);
    }
    __syncthreads();

    for (int rr = 0; rr < 8; ++rr) {
        int r = rh * 8 + rr;
        f32x4 zq[4], zk[4];
#pragma unroll
        for (int mt = 0; mt < 4; ++mt) { zq[mt] = (f32x4)(0.f); zk[mt] = (f32x4)(0.f); }
        const unsigned short* bqp = Wb + (size_t)(r * 64 + pcol) * 256;
        const unsigned short* bkp = bqp + (size_t)1024 * 256;
#pragma unroll
        for (int kk = 0; kk < 8; ++kk) {
            int co = kk * 32 + quad * 8;
            bf16x8 bq = *(const bf16x8*)(bqp + co);
            bf16x8 bk = *(const bf16x8*)(bkp + co);
#pragma unroll
            for (int mt = 0; mt < 4; ++mt) {
                bf16x8 af = *(const bf16x8*)(&As[(mt * 16 + lcol) * AP4 + co]);
                zq[mt] = __builtin_amdgcn_mfma_f32_16x16x32_bf16(af, bq, zq[mt], 0, 0, 0);
                zk[mt] = __builtin_amdgcn_mfma_f32_16x16x32_bf16(af, bk, zk[mt], 0, 0, 0);
            }
        }
        // lane holds Z[bgl = mt*4+quad][n = reg][p = pcol]
#pragma unroll
        for (int mt = 0; mt < 4; ++mt) {
            float t1 = zq[mt].x * zk[mt].x + zq[mt].y * zk[mt].y +
                       zq[mt].z * zk[mt].z + zq[mt].w * zk[mt].w;
            float sq = zq[mt].x + zq[mt].y + zq[mt].z + zq[mt].w;
            float sk = zk[mt].x + zk[mt].y + zk[mt].z + zk[mt].w;
            float t2 = sq * sk;
#pragma unroll
            for (int off = 1; off < 16; off <<= 1) {
                t1 += __shfl_xor(t1, off, 64);
                t2 += __shfl_xor(t2, off, 64);
            }
            if (lcol == 0) {
                int bgl = mt * 4 + quad;
                Tp[((w * 16 + bgl) * 2 + 0) * 8 + rr] = t1;
                Tp[((w * 16 + bgl) * 2 + 1) * 8 + rr] = t2;
            }
        }
    }
    __syncthreads();

    // partial out[bg][f] over this block's 8 r -> atomicAdd
    int f = t & 63, grp = t >> 6;
#pragma unroll
    for (int i = 0; i < 4; ++i) {
        int bgl = grp * 4 + i;
        float a = 0.f;
#pragma unroll
        for (int rr = 0; rr < 8; ++rr) {
            int r = rh * 8 + rr;
            float T1 = Tp[((0 * 16 + bgl) * 2 + 0) * 8 + rr] + Tp[((1 * 16 + bgl) * 2 + 0) * 8 + rr] +
                       Tp[((2 * 16 + bgl) * 2 + 0) * 8 + rr] + Tp[((3 * 16 + bgl) * 2 + 0) * 8 + rr];
            float T2 = Tp[((0 * 16 + bgl) * 2 + 1) * 8 + rr] + Tp[((1 * 16 + bgl) * 2 + 1) * 8 + rr] +
                       Tp[((2 * 16 + bgl) * 2 + 1) * 8 + rr] + Tp[((3 * 16 + bgl) * 2 + 1) * 8 + rr];
            a += coef[f * 16 + r] * T1 + coef[1024 + f * 16 + r] * T2;
        }
        atomicAdd(&out[(size_t)(bg0 + bgl) * NF_ + f], a);
    }
}

// ---------------------------------------------------------------------------
extern "C" void kernel_launch(void* const* d_in, const int* in_sizes, int n_in,
                              void* d_out, int out_size, void* d_ws, size_t ws_size,
                              hipStream_t stream) {
    const float* x         = (const float*)d_in[0];
    const float* filters   = (const float*)d_in[1];
    const float* query_emb = (const float*)d_in[2];
    const float* Wk_map    = (const float*)d_in[3];
    const float* Wq        = (const float*)d_in[4];
    const float* Wk        = (const float*)d_in[5];
    float* out = (float*)d_out;

    char* p = (char*)d_ws;
    unsigned short* xTb  = (unsigned short*)p;  p += (size_t)B_*D_*N_*2;   // 67.1 MB
    unsigned short* kbp  = (unsigned short*)p;  p += (size_t)B_*N_*KD_*2;  // 16.8 MB
    unsigned short* gobj = (unsigned short*)p;  p += (size_t)B_*Q_*D_*2;   // 12.6 MB
    unsigned short* Wb   = (unsigned short*)p;  p += (size_t)2048*256*2;   //  1.0 MB
    float*          coef = (float*)p;           p += 2048*4;
    unsigned short* qeb  = (unsigned short*)p;  p += (size_t)Q_*KD_*2;
    unsigned short* WkTb = (unsigned short*)p;  p += (size_t)KD_*D_*2;     // 32 KB

    hipMemsetAsync(out, 0, (size_t)B_ * G_ * NF_ * sizeof(float), stream);

    hipLaunchKernelGGL(prep_kernel, dim3(148), dim3(256), 0, stream,
                       filters, query_emb, Wk_map, Wq, Wk, coef, qeb, WkTb, Wb);
    hipLaunchKernelGGL(xt_kernel, dim3(8, 4, 128), dim3(256), 0, stream,
                       x, xTb);
    hipLaunchKernelGGL(kproj2_kernel, dim3(16, 128), dim3(256), 0, stream,
                       x, WkTb, kbp);
    hipLaunchKernelGGL(attn4_kernel, dim3(256), dim3(512), 0, stream,
                       qeb, kbp, xTb, gobj);
    hipLaunchKernelGGL(rel5_kernel, dim3(1024), dim3(256), 0, stream,
                       gobj, Wb, coef, out);
}

// Round 8
// 425.533 us; speedup vs baseline: 1.0139x; 1.0139x over previous
//
#include <hip/hip_runtime.h>
#include <math.h>

#define B_   128
#define N_   1024
#define D_   256
#define G_   64
#define GSZ_ 3
#define RD_  16
#define KD_  64
#define PD_  64
#define NF_  64
#define Q_   (G_*GSZ_)   // 192

typedef __attribute__((ext_vector_type(8))) short bf16x8;   // 8 bf16 = 4 VGPRs
typedef __attribute__((ext_vector_type(4))) float f32x4;

__device__ __forceinline__ unsigned short f2bf(float f) {
    unsigned int u = __float_as_uint(f);
    u += 0x7fffu + ((u >> 16) & 1u);       // RNE
    return (unsigned short)(u >> 16);
}

// ---------------------------------------------------------------------------
// prep_kernel: fused one-time prep.
//   blocks   0..31 : Wb[col][d] bf16 (col = qk*1024 + r*64 + p)
//   blocks  32..95 : WkTb[kd][d] = bf16(Wk_map[d][kd])
//   blocks  96..143: qeb = bf16(query_emb * 0.125)
//   blocks 144..147: coef — S3 orbit-collapsed filter coefs (c1, c2)
// ---------------------------------------------------------------------------
__global__ __launch_bounds__(256)
void prep_kernel(const float* __restrict__ filters,
                 const float* __restrict__ qe,
                 const float* __restrict__ Wk_map,
                 const float* __restrict__ Wq,
                 const float* __restrict__ Wk,
                 float* __restrict__ coef,
                 unsigned short* __restrict__ qeb,
                 unsigned short* __restrict__ WkTb,
                 unsigned short* __restrict__ Wb) {
    __shared__ unsigned short wt[64 * 264];
    int bb = blockIdx.x, t = threadIdx.x;
    if (bb < 32) {
        int qk = bb >> 4, r = bb & 15;
        const float* W = qk ? Wk : Wq;
#pragma unroll
        for (int i = 0; i < 16; ++i) {
            int flat = i * 256 + t;            // 4096: 256 d x 16 p4
            int d = flat >> 4, p4 = flat & 15;
            float4 v = *(const float4*)(W + ((size_t)r * 256 + d) * 64 + p4 * 4);
            wt[(p4 * 4 + 0) * 264 + d] = f2bf(v.x);
            wt[(p4 * 4 + 1) * 264 + d] = f2bf(v.y);
            wt[(p4 * 4 + 2) * 264 + d] = f2bf(v.z);
            wt[(p4 * 4 + 3) * 264 + d] = f2bf(v.w);
        }
        __syncthreads();
#pragma unroll
        for (int i = 0; i < 8; ++i) {
            int flat = i * 256 + t;            // 2048: 64 p x 32 segs
            int p = flat >> 5, seg = flat & 31;
            *(uint4*)(Wb + ((size_t)(qk * 1024 + r * 64 + p)) * 256 + seg * 8) =
                *(const uint4*)(&wt[p * 264 + seg * 8]);
        }
    } else if (bb < 96) {
        int i = (bb - 32) * 256 + t;           // [0, 16384)
        int kd = i >> 8, d = i & 255;
        WkTb[kd * 256 + d] = f2bf(Wk_map[d * 64 + kd]);
    } else if (bb < 144) {
        int i = (bb - 96) * 256 + t;
        if (i < Q_ * KD_) qeb[i] = f2bf(qe[i] * 0.125f);
    } else {
        int flat = (bb - 144) * 256 + t;
        if (flat < NF_ * RD_) {
            int f = flat >> 4, r = flat & 15;
            const float* F = filters + f * 144 + r;
            float diag = F[0] + F[48 + 16] + F[96 + 32];
            float all = 0.f;
#pragma unroll
            for (int u = 0; u < 3; ++u)
#pragma unroll
                for (int v = 0; v < 3; ++v) all += F[u * 48 + v * 16];
            float a = diag * (1.f / 3.f);
            float b = (all - diag) * (1.f / 6.f);
            coef[f * 16 + r] = a - b;
            coef[1024 + f * 16 + r] = b;
        }
    }
}

// ---------------------------------------------------------------------------
// xt_kernel: xTb[b][d][n] = bf16(x[b][n][d]). Tile 128n x 64d through LDS.
// ---------------------------------------------------------------------------
__global__ __launch_bounds__(256)
void xt_kernel(const float* __restrict__ x,
               unsigned short* __restrict__ xTb) {
    __shared__ float xs[128][65];
    int b = blockIdx.z, d0 = blockIdx.y * 64, n0 = blockIdx.x * 128;
    int t = threadIdx.x;
#pragma unroll
    for (int i = 0; i < 8; ++i) {
        int f = i * 256 + t;
        int row = f >> 4, c4 = f & 15;       // 128 n-rows x 16 float4
        float4 v = *(const float4*)(x + ((size_t)b * N_ + n0 + row) * D_ + d0 + c4 * 4);
        xs[row][c4 * 4 + 0] = v.x; xs[row][c4 * 4 + 1] = v.y;
        xs[row][c4 * 4 + 2] = v.z; xs[row][c4 * 4 + 3] = v.w;
    }
    __syncthreads();
#pragma unroll
    for (int i = 0; i < 4; ++i) {
        int f = i * 256 + t;
        int dr = f >> 4, seg = f & 15;       // 64 d-rows x 16 n-chunks of 8
        uint4 uv;
        unsigned int* up = (unsigned int*)&uv;
#pragma unroll
        for (int j = 0; j < 4; ++j) {
            unsigned int lo = f2bf(xs[seg * 8 + 2 * j][dr]);
            unsigned int hi = f2bf(xs[seg * 8 + 2 * j + 1][dr]);
            up[j] = lo | (hi << 16);
        }
        *(uint4*)(xTb + ((size_t)b * D_ + d0 + dr) * N_ + n0 + seg * 8) = uv;
    }
}

// ---------------------------------------------------------------------------
// kproj2: k = x@Wk_map + PE -> kb bf16 [b][n][kd] via MFMA on C[kd][n].
// ---------------------------------------------------------------------------
#define WKP 264   // 256+8 bf16 pad, 16B-aligned rows

__global__ __launch_bounds__(256, 2)
void kproj2_kernel(const float* __restrict__ x,
                   const unsigned short* __restrict__ WkTb,
                   unsigned short* __restrict__ kb) {
    __shared__ unsigned short wkts[64 * WKP];
    __shared__ unsigned short xs[64 * WKP];
    __shared__ unsigned short Ks[64 * 72];
    int b = blockIdx.y, n0 = blockIdx.x * 64;
    int t = threadIdx.x, w = t >> 6, lane = t & 63;
    int quad = lane >> 4, lcol = lane & 15;

#pragma unroll
    for (int i = 0; i < 8; ++i) {
        int f = i * 256 + t;
        int row = f >> 5, seg = f & 31;
        *(uint4*)(&wkts[row * WKP + seg * 8]) = *(const uint4*)(WkTb + row * 256 + seg * 8);
    }
#pragma unroll
    for (int i = 0; i < 16; ++i) {
        int f = i * 256 + t;
        int row = f >> 6, c4 = f & 63;
        float4 v = *(const float4*)(x + ((size_t)b * N_ + n0 + row) * D_ + c4 * 4);
        uint2 uv;
        uv.x = (unsigned int)f2bf(v.x) | ((unsigned int)f2bf(v.y) << 16);
        uv.y = (unsigned int)f2bf(v.z) | ((unsigned int)f2bf(v.w) << 16);
        *(uint2*)(&xs[row * WKP + c4 * 4]) = uv;
    }
    __syncthreads();

    f32x4 z[4];
#pragma unroll
    for (int mt = 0; mt < 4; ++mt) z[mt] = (f32x4)(0.f);
#pragma unroll
    for (int kk = 0; kk < 8; ++kk) {
        bf16x8 bf = *(const bf16x8*)(&xs[(w * 16 + lcol) * WKP + kk * 32 + quad * 8]);
#pragma unroll
        for (int mt = 0; mt < 4; ++mt) {
            bf16x8 af = *(const bf16x8*)(&wkts[(mt * 16 + lcol) * WKP + kk * 32 + quad * 8]);
            z[mt] = __builtin_amdgcn_mfma_f32_16x16x32_bf16(af, bf, z[mt], 0, 0, 0);
        }
    }

    int nl = w * 16 + lcol;
    int n = n0 + nl;
#pragma unroll
    for (int mt = 0; mt < 4; ++mt)
#pragma unroll
        for (int r = 0; r < 4; ++r) {
            int kd = mt * 16 + quad * 4 + r;
            float freq  = expf(-(float)(kd >> 1) * (logf(10000.0f) / 32.0f));
            float angle = (float)n * freq;
            float pe    = (kd & 1) ? cosf(angle) : sinf(angle);
            Ks[nl * 72 + kd] = f2bf(z[mt][r] + pe);
        }
    __syncthreads();

#pragma unroll
    for (int i = 0; i < 2; ++i) {
        int f = i * 256 + t;
        int row = f >> 3, seg = f & 7;
        *(uint4*)(kb + ((size_t)b * N_ + n0 + row) * KD_ + seg * 8) =
            *(const uint4*)(&Ks[row * 72 + seg * 8]);
    }
}

// ---------------------------------------------------------------------------
// attn4: per block = (b, q-half of 96), 512 threads. Chunks of 128 n.
// S: wave w owns n-cols w*16+lcol. PV: wave w owns d-tiles {w, 8+w}.
// B-frags straight from global; only the P C->A LDS round trip syncs.
// ---------------------------------------------------------------------------
#define PSP2 136   // 128+8

__global__ __launch_bounds__(512, 2)
void attn4_kernel(const unsigned short* __restrict__ qeb,
                  const unsigned short* __restrict__ kb,
                  const unsigned short* __restrict__ xTb,
                  unsigned short* __restrict__ gobj) {
    __shared__ unsigned short ps[96 * PSP2];
    __shared__ float Rs[96][8];
    __shared__ float invs[96];

    int b = blockIdx.x >> 1, qh = blockIdx.x & 1;
    int t = threadIdx.x, w = t >> 6, lane = t & 63;
    int quad = lane >> 4, lcol = lane & 15;
    int q0 = qh * 96;

    bf16x8 qef[6][2];
#pragma unroll
    for (int mt = 0; mt < 6; ++mt)
#pragma unroll
        for (int ks = 0; ks < 2; ++ks)
            qef[mt][ks] = *(const bf16x8*)(qeb + (q0 + mt * 16 + lcol) * KD_ + ks * 32 + quad * 8);

    f32x4 acc[2][6];
#pragma unroll
    for (int i = 0; i < 2; ++i)
#pragma unroll
        for (int mt = 0; mt < 6; ++mt) acc[i][mt] = (f32x4)(0.f);
    float rsum[6][4];
#pragma unroll
    for (int mt = 0; mt < 6; ++mt)
#pragma unroll
        for (int r = 0; r < 4; ++r) rsum[mt][r] = 0.f;

    const unsigned short* kbB = kb + (size_t)b * N_ * KD_;
    const unsigned short* xtB = xTb + (size_t)b * D_ * N_;

    for (int c = 0; c < 8; ++c) {
        f32x4 s[6];
#pragma unroll
        for (int mt = 0; mt < 6; ++mt) s[mt] = (f32x4)(0.f);
#pragma unroll
        for (int ks = 0; ks < 2; ++ks) {
            bf16x8 bf = *(const bf16x8*)(kbB + (size_t)(c * 128 + w * 16 + lcol) * KD_ + ks * 32 + quad * 8);
#pragma unroll
            for (int mt = 0; mt < 6; ++mt)
                s[mt] = __builtin_amdgcn_mfma_f32_16x16x32_bf16(qef[mt][ks], bf, s[mt], 0, 0, 0);
        }
#pragma unroll
        for (int mt = 0; mt < 6; ++mt)
#pragma unroll
            for (int r = 0; r < 4; ++r) {
                float e = __expf(s[mt][r]);
                s[mt][r] = e;
                rsum[mt][r] += e;
            }
        __syncthreads();   // prior chunk's PV done reading ps
#pragma unroll
        for (int mt = 0; mt < 6; ++mt)
#pragma unroll
            for (int r = 0; r < 4; ++r)
                ps[(mt * 16 + quad * 4 + r) * PSP2 + w * 16 + lcol] = f2bf(s[mt][r]);
        __syncthreads();

#pragma unroll
        for (int ks = 0; ks < 4; ++ks) {
            bf16x8 af[6];
#pragma unroll
            for (int mt = 0; mt < 6; ++mt)
                af[mt] = *(const bf16x8*)(ps + (mt * 16 + lcol) * PSP2 + ks * 32 + quad * 8);
#pragma unroll
            for (int i = 0; i < 2; ++i) {
                int dt = i * 8 + w;
                bf16x8 bf = *(const bf16x8*)(xtB + (size_t)(dt * 16 + lcol) * N_ + c * 128 + ks * 32 + quad * 8);
#pragma unroll
                for (int mt = 0; mt < 6; ++mt)
                    acc[i][mt] = __builtin_amdgcn_mfma_f32_16x16x32_bf16(af[mt], bf, acc[i][mt], 0, 0, 0);
            }
        }
    }

#pragma unroll
    for (int mt = 0; mt < 6; ++mt)
#pragma unroll
        for (int r = 0; r < 4; ++r) {
            float v = rsum[mt][r];
            v += __shfl_xor(v, 1, 64);
            v += __shfl_xor(v, 2, 64);
            v += __shfl_xor(v, 4, 64);
            v += __shfl_xor(v, 8, 64);
            rsum[mt][r] = v;
        }
    if (lcol == 0) {
#pragma unroll
        for (int mt = 0; mt < 6; ++mt)
#pragma unroll
            for (int r = 0; r < 4; ++r)
                Rs[mt * 16 + quad * 4 + r][w] = rsum[mt][r];
    }
    __syncthreads();
    if (t < 96) {
        float s8 = 0.f;
#pragma unroll
        for (int ww = 0; ww < 8; ++ww) s8 += Rs[t][ww];
        invs[t] = 1.0f / s8;
    }
    __syncthreads();

    unsigned short* gB = gobj + ((size_t)b * Q_ + q0) * D_;
#pragma unroll
    for (int i = 0; i < 2; ++i) {
        int dt = i * 8 + w;
#pragma unroll
        for (int mt = 0; mt < 6; ++mt)
#pragma unroll
            for (int r = 0; r < 4; ++r) {
                int q = mt * 16 + quad * 4 + r;
                gB[q * D_ + dt * 16 + lcol] = f2bf(acc[i][mt][r] * invs[q]);
            }
    }
}

// ---------------------------------------------------------------------------
// rel6: rel5's barrier-free MFMA core, r split across 2 blocks (grid 1024,
// LDS 37.9KB -> 4 blocks/CU, 16 waves/CU). NO atomics: blocks write
// disjoint Tsum[bg][2][16] entries; tcoef does the coef contraction.
// ---------------------------------------------------------------------------
#define AP4 264

__global__ __launch_bounds__(256, 4)
void rel6_kernel(const unsigned short* __restrict__ gobj,
                 const unsigned short* __restrict__ Wb,
                 float* __restrict__ Tsum) {
    __shared__ unsigned short As[64 * AP4];
    __shared__ float Tp[4 * 16 * 2 * 8];   // [w][bgl(16)][T1|T2][rr(8)] = 4KB

    int t = threadIdx.x, w = t >> 6, lane = t & 63;
    int quad = lane >> 4, lcol = lane & 15;
    int bg0 = (blockIdx.x >> 1) * 16;
    int rh  = blockIdx.x & 1;
    int pcol = w * 16 + lcol;

    // zero pad rows (row%4==3): 16 rows x 32 uint4
#pragma unroll
    for (int i = 0; i < 2; ++i) {
        int idx = i * 256 + t;
        int r3 = idx >> 5, c4 = idx & 31;
        uint4 zz; zz.x = zz.y = zz.z = zz.w = 0u;
        *(uint4*)(&As[(r3 * 4 + 3) * AP4 + c4 * 8]) = zz;
    }
    // stage 48 gobj rows, row = (j/3)*4 + j%3
#pragma unroll
    for (int i = 0; i < 6; ++i) {
        int idx = i * 256 + t;
        int j = idx >> 5, c4 = idx & 31;
        *(uint4*)(&As[((j / 3) * 4 + (j % 3)) * AP4 + c4 * 8]) =
            *(const uint4*)(gobj + ((size_t)(bg0 * 3 + j)) * 256 + c4 * 8);
    }
    __syncthreads();

    for (int rr = 0; rr < 8; ++rr) {
        int r = rh * 8 + rr;
        f32x4 zq[4], zk[4];
#pragma unroll
        for (int mt = 0; mt < 4; ++mt) { zq[mt] = (f32x4)(0.f); zk[mt] = (f32x4)(0.f); }
        const unsigned short* bqp = Wb + (size_t)(r * 64 + pcol) * 256;
        const unsigned short* bkp = bqp + (size_t)1024 * 256;
#pragma unroll
        for (int kk = 0; kk < 8; ++kk) {
            int co = kk * 32 + quad * 8;
            bf16x8 bq = *(const bf16x8*)(bqp + co);
            bf16x8 bk = *(const bf16x8*)(bkp + co);
#pragma unroll
            for (int mt = 0; mt < 4; ++mt) {
                bf16x8 af = *(const bf16x8*)(&As[(mt * 16 + lcol) * AP4 + co]);
                zq[mt] = __builtin_amdgcn_mfma_f32_16x16x32_bf16(af, bq, zq[mt], 0, 0, 0);
                zk[mt] = __builtin_amdgcn_mfma_f32_16x16x32_bf16(af, bk, zk[mt], 0, 0, 0);
            }
        }
        // lane holds Z[bgl = mt*4+quad][n = reg][p = pcol]
#pragma unroll
        for (int mt = 0; mt < 4; ++mt) {
            float t1 = zq[mt].x * zk[mt].x + zq[mt].y * zk[mt].y +
                       zq[mt].z * zk[mt].z + zq[mt].w * zk[mt].w;
            float sq = zq[mt].x + zq[mt].y + zq[mt].z + zq[mt].w;
            float sk = zk[mt].x + zk[mt].y + zk[mt].z + zk[mt].w;
            float t2 = sq * sk;
#pragma unroll
            for (int off = 1; off < 16; off <<= 1) {
                t1 += __shfl_xor(t1, off, 64);
                t2 += __shfl_xor(t2, off, 64);
            }
            if (lcol == 0) {
                int bgl = mt * 4 + quad;
                Tp[((w * 16 + bgl) * 2 + 0) * 8 + rr] = t1;
                Tp[((w * 16 + bgl) * 2 + 1) * 8 + rr] = t2;
            }
        }
    }
    __syncthreads();

    // write disjoint Tsum entries: 256 threads == 16 bgl x 2 tt x 8 rr
    {
        int bgl = t >> 4, idx = t & 15;
        int tt = idx >> 3, rr = idx & 7;
        float v = Tp[((0 * 16 + bgl) * 2 + tt) * 8 + rr] +
                  Tp[((1 * 16 + bgl) * 2 + tt) * 8 + rr] +
                  Tp[((2 * 16 + bgl) * 2 + tt) * 8 + rr] +
                  Tp[((3 * 16 + bgl) * 2 + tt) * 8 + rr];
        Tsum[((size_t)(bg0 + bgl) * 2 + tt) * 16 + rh * 8 + rr] = v;
    }
}

// ---------------------------------------------------------------------------
// tcoef: out[bg][f] = sum_r c1[f,r]*T1[bg,r] + c2[f,r]*T2[bg,r].
// 4 bg per block; coef staged in LDS; T reads broadcast; writes coalesced.
// Fully overwrites out (no memset needed).
// ---------------------------------------------------------------------------
__global__ __launch_bounds__(256)
void tcoef_kernel(const float* __restrict__ Tsum,
                  const float* __restrict__ coef,
                  float* __restrict__ out) {
    __shared__ float cs[2048];
    int t = threadIdx.x;
#pragma unroll
    for (int i = 0; i < 8; ++i) cs[i * 256 + t] = coef[i * 256 + t];
    __syncthreads();
    int f = t & 63, i = t >> 6;
    int bg = blockIdx.x * 4 + i;
    const float* Tb = Tsum + (size_t)bg * 32;
    float a = 0.f;
#pragma unroll
    for (int r = 0; r < 16; ++r)
        a += cs[f * 16 + r] * Tb[r] + cs[1024 + f * 16 + r] * Tb[16 + r];
    out[(size_t)bg * NF_ + f] = a;
}

// ---------------------------------------------------------------------------
extern "C" void kernel_launch(void* const* d_in, const int* in_sizes, int n_in,
                              void* d_out, int out_size, void* d_ws, size_t ws_size,
                              hipStream_t stream) {
    const float* x         = (const float*)d_in[0];
    const float* filters   = (const float*)d_in[1];
    const float* query_emb = (const float*)d_in[2];
    const float* Wk_map    = (const float*)d_in[3];
    const float* Wq        = (const float*)d_in[4];
    const float* Wk        = (const float*)d_in[5];
    float* out = (float*)d_out;

    char* p = (char*)d_ws;
    unsigned short* xTb  = (unsigned short*)p;  p += (size_t)B_*D_*N_*2;   // 67.1 MB
    unsigned short* kbp  = (unsigned short*)p;  p += (size_t)B_*N_*KD_*2;  // 16.8 MB
    unsigned short* gobj = (unsigned short*)p;  p += (size_t)B_*Q_*D_*2;   // 12.6 MB
    unsigned short* Wb   = (unsigned short*)p;  p += (size_t)2048*256*2;   //  1.0 MB
    float*          coef = (float*)p;           p += 2048*4;
    unsigned short* qeb  = (unsigned short*)p;  p += (size_t)Q_*KD_*2;
    unsigned short* WkTb = (unsigned short*)p;  p += (size_t)KD_*D_*2;     // 32 KB
    float*          Tsum = (float*)p;           p += (size_t)B_*G_*32*4;   //  1.0 MB

    hipLaunchKernelGGL(prep_kernel, dim3(148), dim3(256), 0, stream,
                       filters, query_emb, Wk_map, Wq, Wk, coef, qeb, WkTb, Wb);
    hipLaunchKernelGGL(xt_kernel, dim3(8, 4, 128), dim3(256), 0, stream,
                       x, xTb);
    hipLaunchKernelGGL(kproj2_kernel, dim3(16, 128), dim3(256), 0, stream,
                       x, WkTb, kbp);
    hipLaunchKernelGGL(attn4_kernel, dim3(256), dim3(512), 0, stream,
                       qeb, kbp, xTb, gobj);
    hipLaunchKernelGGL(rel6_kernel, dim3(1024), dim3(256), 0, stream,
                       gobj, Wb, Tsum);
    hipLaunchKernelGGL(tcoef_kernel, dim3(2048), dim3(256), 0, stream,
                       Tsum, coef, out);
}

// Round 9
// 421.125 us; speedup vs baseline: 1.0246x; 1.0105x over previous
//
#include <hip/hip_runtime.h>
#include <math.h>

#define B_   128
#define N_   1024
#define D_   256
#define G_   64
#define GSZ_ 3
#define RD_  16
#define KD_  64
#define PD_  64
#define NF_  64
#define Q_   (G_*GSZ_)   // 192

typedef __attribute__((ext_vector_type(8))) short bf16x8;   // 8 bf16 = 4 VGPRs
typedef __attribute__((ext_vector_type(4))) float f32x4;

__device__ __forceinline__ unsigned short f2bf(float f) {
    unsigned int u = __float_as_uint(f);
    u += 0x7fffu + ((u >> 16) & 1u);       // RNE
    return (unsigned short)(u >> 16);
}

// ---------------------------------------------------------------------------
// prep_kernel: fused one-time prep.
//   blocks   0..31 : Wb[col][d] bf16 (col = qk*1024 + r*64 + p)
//   blocks  32..95 : WkTb[kd][d] = bf16(Wk_map[d][kd])
//   blocks  96..143: qeb = bf16(query_emb * 0.125)
//   blocks 144..147: coef — S3 orbit-collapsed filter coefs (c1, c2)
// ---------------------------------------------------------------------------
__global__ __launch_bounds__(256)
void prep_kernel(const float* __restrict__ filters,
                 const float* __restrict__ qe,
                 const float* __restrict__ Wk_map,
                 const float* __restrict__ Wq,
                 const float* __restrict__ Wk,
                 float* __restrict__ coef,
                 unsigned short* __restrict__ qeb,
                 unsigned short* __restrict__ WkTb,
                 unsigned short* __restrict__ Wb) {
    __shared__ unsigned short wt[64 * 264];
    int bb = blockIdx.x, t = threadIdx.x;
    if (bb < 32) {
        int qk = bb >> 4, r = bb & 15;
        const float* W = qk ? Wk : Wq;
#pragma unroll
        for (int i = 0; i < 16; ++i) {
            int flat = i * 256 + t;            // 4096: 256 d x 16 p4
            int d = flat >> 4, p4 = flat & 15;
            float4 v = *(const float4*)(W + ((size_t)r * 256 + d) * 64 + p4 * 4);
            wt[(p4 * 4 + 0) * 264 + d] = f2bf(v.x);
            wt[(p4 * 4 + 1) * 264 + d] = f2bf(v.y);
            wt[(p4 * 4 + 2) * 264 + d] = f2bf(v.z);
            wt[(p4 * 4 + 3) * 264 + d] = f2bf(v.w);
        }
        __syncthreads();
#pragma unroll
        for (int i = 0; i < 8; ++i) {
            int flat = i * 256 + t;            // 2048: 64 p x 32 segs
            int p = flat >> 5, seg = flat & 31;
            *(uint4*)(Wb + ((size_t)(qk * 1024 + r * 64 + p)) * 256 + seg * 8) =
                *(const uint4*)(&wt[p * 264 + seg * 8]);
        }
    } else if (bb < 96) {
        int i = (bb - 32) * 256 + t;           // [0, 16384)
        int kd = i >> 8, d = i & 255;
        WkTb[kd * 256 + d] = f2bf(Wk_map[d * 64 + kd]);
    } else if (bb < 144) {
        int i = (bb - 96) * 256 + t;
        if (i < Q_ * KD_) qeb[i] = f2bf(qe[i] * 0.125f);
    } else {
        int flat = (bb - 144) * 256 + t;
        if (flat < NF_ * RD_) {
            int f = flat >> 4, r = flat & 15;
            const float* F = filters + f * 144 + r;
            float diag = F[0] + F[48 + 16] + F[96 + 32];
            float all = 0.f;
#pragma unroll
            for (int u = 0; u < 3; ++u)
#pragma unroll
                for (int v = 0; v < 3; ++v) all += F[u * 48 + v * 16];
            float a = diag * (1.f / 3.f);
            float b = (all - diag) * (1.f / 6.f);
            coef[f * 16 + r] = a - b;
            coef[1024 + f * 16 + r] = b;
        }
    }
}

// ---------------------------------------------------------------------------
// xt_kernel: xTb[b][d][n] = bf16(x[b][n][d]). Tile 128n x 64d through LDS.
// ---------------------------------------------------------------------------
__global__ __launch_bounds__(256)
void xt_kernel(const float* __restrict__ x,
               unsigned short* __restrict__ xTb) {
    __shared__ float xs[128][65];
    int b = blockIdx.z, d0 = blockIdx.y * 64, n0 = blockIdx.x * 128;
    int t = threadIdx.x;
#pragma unroll
    for (int i = 0; i < 8; ++i) {
        int f = i * 256 + t;
        int row = f >> 4, c4 = f & 15;       // 128 n-rows x 16 float4
        float4 v = *(const float4*)(x + ((size_t)b * N_ + n0 + row) * D_ + d0 + c4 * 4);
        xs[row][c4 * 4 + 0] = v.x; xs[row][c4 * 4 + 1] = v.y;
        xs[row][c4 * 4 + 2] = v.z; xs[row][c4 * 4 + 3] = v.w;
    }
    __syncthreads();
#pragma unroll
    for (int i = 0; i < 4; ++i) {
        int f = i * 256 + t;
        int dr = f >> 4, seg = f & 15;       // 64 d-rows x 16 n-chunks of 8
        uint4 uv;
        unsigned int* up = (unsigned int*)&uv;
#pragma unroll
        for (int j = 0; j < 4; ++j) {
            unsigned int lo = f2bf(xs[seg * 8 + 2 * j][dr]);
            unsigned int hi = f2bf(xs[seg * 8 + 2 * j + 1][dr]);
            up[j] = lo | (hi << 16);
        }
        *(uint4*)(xTb + ((size_t)b * D_ + d0 + dr) * N_ + n0 + seg * 8) = uv;
    }
}

// ---------------------------------------------------------------------------
// kproj2: k = x@Wk_map + PE -> kb bf16 [b][n][kd] via MFMA on C[kd][n].
// ---------------------------------------------------------------------------
#define WKP 264   // 256+8 bf16 pad, 16B-aligned rows

__global__ __launch_bounds__(256, 2)
void kproj2_kernel(const float* __restrict__ x,
                   const unsigned short* __restrict__ WkTb,
                   unsigned short* __restrict__ kb) {
    __shared__ unsigned short wkts[64 * WKP];
    __shared__ unsigned short xs[64 * WKP];
    __shared__ unsigned short Ks[64 * 72];
    int b = blockIdx.y, n0 = blockIdx.x * 64;
    int t = threadIdx.x, w = t >> 6, lane = t & 63;
    int quad = lane >> 4, lcol = lane & 15;

#pragma unroll
    for (int i = 0; i < 8; ++i) {
        int f = i * 256 + t;
        int row = f >> 5, seg = f & 31;
        *(uint4*)(&wkts[row * WKP + seg * 8]) = *(const uint4*)(WkTb + row * 256 + seg * 8);
    }
#pragma unroll
    for (int i = 0; i < 16; ++i) {
        int f = i * 256 + t;
        int row = f >> 6, c4 = f & 63;
        float4 v = *(const float4*)(x + ((size_t)b * N_ + n0 + row) * D_ + c4 * 4);
        uint2 uv;
        uv.x = (unsigned int)f2bf(v.x) | ((unsigned int)f2bf(v.y) << 16);
        uv.y = (unsigned int)f2bf(v.z) | ((unsigned int)f2bf(v.w) << 16);
        *(uint2*)(&xs[row * WKP + c4 * 4]) = uv;
    }
    __syncthreads();

    f32x4 z[4];
#pragma unroll
    for (int mt = 0; mt < 4; ++mt) z[mt] = (f32x4)(0.f);
#pragma unroll
    for (int kk = 0; kk < 8; ++kk) {
        bf16x8 bf = *(const bf16x8*)(&xs[(w * 16 + lcol) * WKP + kk * 32 + quad * 8]);
#pragma unroll
        for (int mt = 0; mt < 4; ++mt) {
            bf16x8 af = *(const bf16x8*)(&wkts[(mt * 16 + lcol) * WKP + kk * 32 + quad * 8]);
            z[mt] = __builtin_amdgcn_mfma_f32_16x16x32_bf16(af, bf, z[mt], 0, 0, 0);
        }
    }

    int nl = w * 16 + lcol;
    int n = n0 + nl;
#pragma unroll
    for (int mt = 0; mt < 4; ++mt)
#pragma unroll
        for (int r = 0; r < 4; ++r) {
            int kd = mt * 16 + quad * 4 + r;
            float freq  = expf(-(float)(kd >> 1) * (logf(10000.0f) / 32.0f));
            float angle = (float)n * freq;
            float pe    = (kd & 1) ? cosf(angle) : sinf(angle);
            Ks[nl * 72 + kd] = f2bf(z[mt][r] + pe);
        }
    __syncthreads();

#pragma unroll
    for (int i = 0; i < 2; ++i) {
        int f = i * 256 + t;
        int row = f >> 3, seg = f & 7;
        *(uint4*)(kb + ((size_t)b * N_ + n0 + row) * KD_ + seg * 8) =
            *(const uint4*)(&Ks[row * 72 + seg * 8]);
    }
}

// ---------------------------------------------------------------------------
// attn5: per block = (b, q-quarter of 48), 512 threads, grid 512 (2 blk/CU,
// 16 waves/CU — 2x attn4's latency hiding). Chunks of 128 n.
// S: wave w owns n-cols w*16+lcol (8 waves x 16 = 128). PV: wave w owns
// d-tiles {w, 8+w}. B-frags direct from global; P does the C->A LDS trip.
// ---------------------------------------------------------------------------
#define PSP2 136   // 128+8

__global__ __launch_bounds__(512, 2)
void attn5_kernel(const unsigned short* __restrict__ qeb,
                  const unsigned short* __restrict__ kb,
                  const unsigned short* __restrict__ xTb,
                  unsigned short* __restrict__ gobj) {
    __shared__ unsigned short ps[48 * PSP2];
    __shared__ float Rs[48][8];
    __shared__ float invs[48];

    int b = blockIdx.x >> 2, qq = blockIdx.x & 3;
    int t = threadIdx.x, w = t >> 6, lane = t & 63;
    int quad = lane >> 4, lcol = lane & 15;
    int q0 = qq * 48;

    bf16x8 qef[3][2];
#pragma unroll
    for (int mt = 0; mt < 3; ++mt)
#pragma unroll
        for (int ks = 0; ks < 2; ++ks)
            qef[mt][ks] = *(const bf16x8*)(qeb + (q0 + mt * 16 + lcol) * KD_ + ks * 32 + quad * 8);

    f32x4 acc[2][3];
#pragma unroll
    for (int i = 0; i < 2; ++i)
#pragma unroll
        for (int mt = 0; mt < 3; ++mt) acc[i][mt] = (f32x4)(0.f);
    float rsum[3][4];
#pragma unroll
    for (int mt = 0; mt < 3; ++mt)
#pragma unroll
        for (int r = 0; r < 4; ++r) rsum[mt][r] = 0.f;

    const unsigned short* kbB = kb + (size_t)b * N_ * KD_;
    const unsigned short* xtB = xTb + (size_t)b * D_ * N_;

    for (int c = 0; c < 8; ++c) {
        f32x4 s[3];
#pragma unroll
        for (int mt = 0; mt < 3; ++mt) s[mt] = (f32x4)(0.f);
#pragma unroll
        for (int ks = 0; ks < 2; ++ks) {
            bf16x8 bf = *(const bf16x8*)(kbB + (size_t)(c * 128 + w * 16 + lcol) * KD_ + ks * 32 + quad * 8);
#pragma unroll
            for (int mt = 0; mt < 3; ++mt)
                s[mt] = __builtin_amdgcn_mfma_f32_16x16x32_bf16(qef[mt][ks], bf, s[mt], 0, 0, 0);
        }
#pragma unroll
        for (int mt = 0; mt < 3; ++mt)
#pragma unroll
            for (int r = 0; r < 4; ++r) {
                float e = __expf(s[mt][r]);
                s[mt][r] = e;
                rsum[mt][r] += e;
            }
        __syncthreads();   // prior chunk's PV done reading ps
#pragma unroll
        for (int mt = 0; mt < 3; ++mt)
#pragma unroll
            for (int r = 0; r < 4; ++r)
                ps[(mt * 16 + quad * 4 + r) * PSP2 + w * 16 + lcol] = f2bf(s[mt][r]);
        __syncthreads();

#pragma unroll
        for (int ks = 0; ks < 4; ++ks) {
            bf16x8 af[3];
#pragma unroll
            for (int mt = 0; mt < 3; ++mt)
                af[mt] = *(const bf16x8*)(ps + (mt * 16 + lcol) * PSP2 + ks * 32 + quad * 8);
#pragma unroll
            for (int i = 0; i < 2; ++i) {
                int dt = i * 8 + w;
                bf16x8 bf = *(const bf16x8*)(xtB + (size_t)(dt * 16 + lcol) * N_ + c * 128 + ks * 32 + quad * 8);
#pragma unroll
                for (int mt = 0; mt < 3; ++mt)
                    acc[i][mt] = __builtin_amdgcn_mfma_f32_16x16x32_bf16(af[mt], bf, acc[i][mt], 0, 0, 0);
            }
        }
    }

#pragma unroll
    for (int mt = 0; mt < 3; ++mt)
#pragma unroll
        for (int r = 0; r < 4; ++r) {
            float v = rsum[mt][r];
            v += __shfl_xor(v, 1, 64);
            v += __shfl_xor(v, 2, 64);
            v += __shfl_xor(v, 4, 64);
            v += __shfl_xor(v, 8, 64);
            rsum[mt][r] = v;
        }
    if (lcol == 0) {
#pragma unroll
        for (int mt = 0; mt < 3; ++mt)
#pragma unroll
            for (int r = 0; r < 4; ++r)
                Rs[mt * 16 + quad * 4 + r][w] = rsum[mt][r];
    }
    __syncthreads();
    if (t < 48) {
        float s8 = 0.f;
#pragma unroll
        for (int ww = 0; ww < 8; ++ww) s8 += Rs[t][ww];
        invs[t] = 1.0f / s8;
    }
    __syncthreads();

    unsigned short* gB = gobj + ((size_t)b * Q_ + q0) * D_;
#pragma unroll
    for (int i = 0; i < 2; ++i) {
        int dt = i * 8 + w;
#pragma unroll
        for (int mt = 0; mt < 3; ++mt)
#pragma unroll
            for (int r = 0; r < 4; ++r) {
                int q = mt * 16 + quad * 4 + r;
                gB[q * D_ + dt * 16 + lcol] = f2bf(acc[i][mt][r] * invs[q]);
            }
    }
}

// ---------------------------------------------------------------------------
// rel7: rel6 with __launch_bounds__(256,3) — the (256,4) cap in rel5/rel6
// forced scratch spills (WRITE_SIZE 72MB of spill stores, FETCH 293MB of
// reloads). Budget 170/wave fits the ~132-reg demand; LDS 37.9KB -> 3
// blocks/CU, 12 waves/CU. No atomics: disjoint Tsum writes + tcoef.
// ---------------------------------------------------------------------------
#define AP4 264

__global__ __launch_bounds__(256, 3)
void rel7_kernel(const unsigned short* __restrict__ gobj,
                 const unsigned short* __restrict__ Wb,
                 float* __restrict__ Tsum) {
    __shared__ unsigned short As[64 * AP4];
    __shared__ float Tp[4 * 16 * 2 * 8];   // [w][bgl(16)][T1|T2][rr(8)] = 4KB

    int t = threadIdx.x, w = t >> 6, lane = t & 63;
    int quad = lane >> 4, lcol = lane & 15;
    int bg0 = (blockIdx.x >> 1) * 16;
    int rh  = blockIdx.x & 1;
    int pcol = w * 16 + lcol;

    // zero pad rows (row%4==3): 16 rows x 32 uint4
#pragma unroll
    for (int i = 0; i < 2; ++i) {
        int idx = i * 256 + t;
        int r3 = idx >> 5, c4 = idx & 31;
        uint4 zz; zz.x = zz.y = zz.z = zz.w = 0u;
        *(uint4*)(&As[(r3 * 4 + 3) * AP4 + c4 * 8]) = zz;
    }
    // stage 48 gobj rows, row = (j/3)*4 + j%3
#pragma unroll
    for (int i = 0; i < 6; ++i) {
        int idx = i * 256 + t;
        int j = idx >> 5, c4 = idx & 31;
        *(uint4*)(&As[((j / 3) * 4 + (j % 3)) * AP4 + c4 * 8]) =
            *(const uint4*)(gobj + ((size_t)(bg0 * 3 + j)) * 256 + c4 * 8);
    }
    __syncthreads();

    for (int rr = 0; rr < 8; ++rr) {
        int r = rh * 8 + rr;
        f32x4 zq[4], zk[4];
#pragma unroll
        for (int mt = 0; mt < 4; ++mt) { zq[mt] = (f32x4)(0.f); zk[mt] = (f32x4)(0.f); }
        const unsigned short* bqp = Wb + (size_t)(r * 64 + pcol) * 256;
        const unsigned short* bkp = bqp + (size_t)1024 * 256;
#pragma unroll
        for (int kk = 0; kk < 8; ++kk) {
            int co = kk * 32 + quad * 8;
            bf16x8 bq = *(const bf16x8*)(bqp + co);
            bf16x8 bk = *(const bf16x8*)(bkp + co);
#pragma unroll
            for (int mt = 0; mt < 4; ++mt) {
                bf16x8 af = *(const bf16x8*)(&As[(mt * 16 + lcol) * AP4 + co]);
                zq[mt] = __builtin_amdgcn_mfma_f32_16x16x32_bf16(af, bq, zq[mt], 0, 0, 0);
                zk[mt] = __builtin_amdgcn_mfma_f32_16x16x32_bf16(af, bk, zk[mt], 0, 0, 0);
            }
        }
        // lane holds Z[bgl = mt*4+quad][n = reg][p = pcol]
#pragma unroll
        for (int mt = 0; mt < 4; ++mt) {
            float t1 = zq[mt].x * zk[mt].x + zq[mt].y * zk[mt].y +
                       zq[mt].z * zk[mt].z + zq[mt].w * zk[mt].w;
            float sq = zq[mt].x + zq[mt].y + zq[mt].z + zq[mt].w;
            float sk = zk[mt].x + zk[mt].y + zk[mt].z + zk[mt].w;
            float t2 = sq * sk;
#pragma unroll
            for (int off = 1; off < 16; off <<= 1) {
                t1 += __shfl_xor(t1, off, 64);
                t2 += __shfl_xor(t2, off, 64);
            }
            if (lcol == 0) {
                int bgl = mt * 4 + quad;
                Tp[((w * 16 + bgl) * 2 + 0) * 8 + rr] = t1;
                Tp[((w * 16 + bgl) * 2 + 1) * 8 + rr] = t2;
            }
        }
    }
    __syncthreads();

    // write disjoint Tsum entries: 256 threads == 16 bgl x 2 tt x 8 rr
    {
        int bgl = t >> 4, idx = t & 15;
        int tt = idx >> 3, rr = idx & 7;
        float v = Tp[((0 * 16 + bgl) * 2 + tt) * 8 + rr] +
                  Tp[((1 * 16 + bgl) * 2 + tt) * 8 + rr] +
                  Tp[((2 * 16 + bgl) * 2 + tt) * 8 + rr] +
                  Tp[((3 * 16 + bgl) * 2 + tt) * 8 + rr];
        Tsum[((size_t)(bg0 + bgl) * 2 + tt) * 16 + rh * 8 + rr] = v;
    }
}

// ---------------------------------------------------------------------------
// tcoef: out[bg][f] = sum_r c1[f,r]*T1[bg,r] + c2[f,r]*T2[bg,r].
// ---------------------------------------------------------------------------
__global__ __launch_bounds__(256)
void tcoef_kernel(const float* __restrict__ Tsum,
                  const float* __restrict__ coef,
                  float* __restrict__ out) {
    __shared__ float cs[2048];
    int t = threadIdx.x;
#pragma unroll
    for (int i = 0; i < 8; ++i) cs[i * 256 + t] = coef[i * 256 + t];
    __syncthreads();
    int f = t & 63, i = t >> 6;
    int bg = blockIdx.x * 4 + i;
    const float* Tb = Tsum + (size_t)bg * 32;
    float a = 0.f;
#pragma unroll
    for (int r = 0; r < 16; ++r)
        a += cs[f * 16 + r] * Tb[r] + cs[1024 + f * 16 + r] * Tb[16 + r];
    out[(size_t)bg * NF_ + f] = a;
}

// ---------------------------------------------------------------------------
extern "C" void kernel_launch(void* const* d_in, const int* in_sizes, int n_in,
                              void* d_out, int out_size, void* d_ws, size_t ws_size,
                              hipStream_t stream) {
    const float* x         = (const float*)d_in[0];
    const float* filters   = (const float*)d_in[1];
    const float* query_emb = (const float*)d_in[2];
    const float* Wk_map    = (const float*)d_in[3];
    const float* Wq        = (const float*)d_in[4];
    const float* Wk        = (const float*)d_in[5];
    float* out = (float*)d_out;

    char* p = (char*)d_ws;
    unsigned short* xTb  = (unsigned short*)p;  p += (size_t)B_*D_*N_*2;   // 67.1 MB
    unsigned short* kbp  = (unsigned short*)p;  p += (size_t)B_*N_*KD_*2;  // 16.8 MB
    unsigned short* gobj = (unsigned short*)p;  p += (size_t)B_*Q_*D_*2;   // 12.6 MB
    unsigned short* Wb   = (unsigned short*)p;  p += (size_t)2048*256*2;   //  1.0 MB
    float*          coef = (float*)p;           p += 2048*4;
    unsigned short* qeb  = (unsigned short*)p;  p += (size_t)Q_*KD_*2;
    unsigned short* WkTb = (unsigned short*)p;  p += (size_t)KD_*D_*2;     // 32 KB
    float*          Tsum = (float*)p;           p += (size_t)B_*G_*32*4;   //  1.0 MB

    hipLaunchKernelGGL(prep_kernel, dim3(148), dim3(256), 0, stream,
                       filters, query_emb, Wk_map, Wq, Wk, coef, qeb, WkTb, Wb);
    hipLaunchKernelGGL(xt_kernel, dim3(8, 4, 128), dim3(256), 0, stream,
                       x, xTb);
    hipLaunchKernelGGL(kproj2_kernel, dim3(16, 128), dim3(256), 0, stream,
                       x, WkTb, kbp);
    hipLaunchKernelGGL(attn5_kernel, dim3(512), dim3(512), 0, stream,
                       qeb, kbp, xTb, gobj);
    hipLaunchKernelGGL(rel7_kernel, dim3(1024), dim3(256), 0, stream,
                       gobj, Wb, Tsum);
    hipLaunchKernelGGL(tcoef_kernel, dim3(2048), dim3(256), 0, stream,
                       Tsum, coef, out);
}